// Round 2
// baseline (30.607 us; speedup 1.0000x reference)
//
#include <hip/hip_runtime.h>

// Contrast-depth loss:
//   d = out - label   (elementwise, [B,32,32] fp32)
//   loss = mean over (b, 8 neighbors, 30x30 centers) of
//          (d[y+dy][x+dx] - d[y][x])^2, centers y,x in [1,30]
//
// R1 design: wave-per-image, direct global loads (L1-served), no LDS,
// no barriers in hot path -> high MLP, latency-tolerant.

#define THREADS 256

__global__ __launch_bounds__(THREADS) void cdl_partial(
    const float* __restrict__ outp,
    const float* __restrict__ labp,
    float* __restrict__ partial,
    int nimg)
{
    const int t    = threadIdx.x;
    const int lane = t & 63;
    const int wid  = t >> 6;
    const int img  = blockIdx.x * 4 + wid;

    float acc = 0.f;

    if (img < nimg) {
        const float* ob = outp + img * 1024;
        const float* lb = labp + img * 1024;

        // 15x15 = 225 2x2-center quads, 64 lanes -> 3 full iters + 1 masked
        #pragma unroll
        for (int i = 0; i < 4; ++i) {
            const int task = i * 64 + lane;
            if (task < 225) {
                const int qy = task / 15;
                const int qx = task - qy * 15;
                const int y = 2 * qy + 1;          // 1,3,...,29
                const int x = 2 * qx + 1;
                const int base = (y - 1) * 32 + (x - 1);   // (x-1) even -> 8B aligned

                float dd[4][4];
                #pragma unroll
                for (int r = 0; r < 4; ++r) {
                    const float2 o0 = *(const float2*)(ob + base + r * 32);
                    const float2 o1 = *(const float2*)(ob + base + r * 32 + 2);
                    const float2 l0 = *(const float2*)(lb + base + r * 32);
                    const float2 l1 = *(const float2*)(lb + base + r * 32 + 2);
                    dd[r][0] = o0.x - l0.x;
                    dd[r][1] = o0.y - l0.y;
                    dd[r][2] = o1.x - l1.x;
                    dd[r][3] = o1.y - l1.y;
                }

                #pragma unroll
                for (int cy = 0; cy < 2; ++cy) {
                    #pragma unroll
                    for (int cx = 0; cx < 2; ++cx) {
                        const float c = dd[cy + 1][cx + 1];
                        #pragma unroll
                        for (int ny = 0; ny < 3; ++ny) {
                            #pragma unroll
                            for (int nx = 0; nx < 3; ++nx) {
                                if (ny == 1 && nx == 1) continue;
                                const float v = dd[cy + ny][cx + nx] - c;
                                acc += v * v;
                            }
                        }
                    }
                }
            }
        }
    }

    // wave reduce, then 4 waves -> 1 value per block
    #pragma unroll
    for (int off = 32; off; off >>= 1) acc += __shfl_down(acc, off, 64);
    __shared__ float red[4];
    if (lane == 0) red[wid] = acc;
    __syncthreads();
    if (t == 0) partial[blockIdx.x] = red[0] + red[1] + red[2] + red[3];
}

__global__ __launch_bounds__(THREADS) void cdl_final(
    const float* __restrict__ partial,
    float* __restrict__ out,
    int np,
    float inv_count)
{
    __shared__ float red[THREADS / 64];
    const int t = threadIdx.x;
    float acc = 0.f;
    for (int i = t; i < np; i += THREADS) acc += partial[i];
    #pragma unroll
    for (int off = 32; off; off >>= 1) acc += __shfl_down(acc, off, 64);
    if ((t & 63) == 0) red[t >> 6] = acc;
    __syncthreads();
    if (t == 0) out[0] = (red[0] + red[1] + red[2] + red[3]) * inv_count;
}

extern "C" void kernel_launch(void* const* d_in, const int* in_sizes, int n_in,
                              void* d_out, int out_size, void* d_ws, size_t ws_size,
                              hipStream_t stream) {
    const float* outp = (const float*)d_in[0];
    const float* labp = (const float*)d_in[1];
    float* partial = (float*)d_ws;
    const int nimg = in_sizes[0] / 1024;              // B (H=W=32)
    const int nblocks = (nimg + 3) / 4;               // 1 image per wave, 4 waves/block
    const float inv_count = 1.0f / ((float)nimg * 8.0f * 900.0f);

    cdl_partial<<<nblocks, THREADS, 0, stream>>>(outp, labp, partial, nimg);
    cdl_final<<<1, THREADS, 0, stream>>>(partial, (float*)d_out, nblocks, inv_count);
}

// Round 3
// 29.387 us; speedup vs baseline: 1.0415x; 1.0415x over previous
//
#include <hip/hip_runtime.h>

// Contrast-depth loss:
//   d = out - label   (elementwise, [B,32,32] fp32)
//   loss = mean over (b, 8 neighbors, 30x30 centers) of
//          (d[y+dy][x+dx] - d[y][x])^2, centers y,x in [1,30]
//
// R3 design: LDS staging (zero overfetch), double-buffered, register-prefetch
// pipeline (1 image ahead), one barrier per image, 8 blocks/CU full occupancy.

#define THREADS 256
#define IPB 8          // images per block
#define STRIDE 36      // LDS row stride in floats: rows stay 16B-aligned

__global__ __launch_bounds__(THREADS, 8) void cdl_partial(
    const float* __restrict__ outp,
    const float* __restrict__ labp,
    float* __restrict__ partial,
    int nimg)
{
    __shared__ float d[2][32][STRIDE];
    const int t   = threadIdx.x;
    const int row = t >> 3;            // 8 float4 per 32-float row
    const int col = (t & 7) << 2;

    const int b0 = blockIdx.x * IPB;
    const float4* op = (const float4*)outp + (long long)b0 * 256 + t;
    const float4* lp = (const float4*)labp + (long long)b0 * 256 + t;

    // quad task: thread t<225 owns 2x2 centers, 4x4 patch at (2qy, 2qx)
    const bool active = t < 225;
    const int qy = t / 15, qx = t - qy * 15;
    const int ry = 2 * qy, cx = 2 * qx;        // cx even -> float2-aligned

    float acc = 0.f;

    // prologue: load image b0
    float4 o = *op, l = *lp;
    float4 dv = make_float4(o.x - l.x, o.y - l.y, o.z - l.z, o.w - l.w);

    const int n = (nimg - b0 < IPB) ? (nimg - b0) : IPB;
    for (int i = 0; i < n; ++i) {
        // issue next image's loads early (latency hides under barrier+compute)
        float4 on, ln;
        const bool more = (i + 1 < n);
        if (more) { on = op[(i + 1) * 256]; ln = lp[(i + 1) * 256]; }

        *(float4*)&d[i & 1][row][col] = dv;
        __syncthreads();

        if (active) {
            const float (*im)[STRIDE] = d[i & 1];
            float dd[4][4];
            #pragma unroll
            for (int r = 0; r < 4; ++r) {
                const float2 a = *(const float2*)&im[ry + r][cx];
                const float2 b = *(const float2*)&im[ry + r][cx + 2];
                dd[r][0] = a.x; dd[r][1] = a.y; dd[r][2] = b.x; dd[r][3] = b.y;
            }
            #pragma unroll
            for (int cyy = 0; cyy < 2; ++cyy) {
                #pragma unroll
                for (int cxx = 0; cxx < 2; ++cxx) {
                    const float c = dd[cyy + 1][cxx + 1];
                    #pragma unroll
                    for (int ny = 0; ny < 3; ++ny) {
                        #pragma unroll
                        for (int nx = 0; nx < 3; ++nx) {
                            if (ny == 1 && nx == 1) continue;
                            const float v = dd[cyy + ny][cxx + nx] - c;
                            acc += v * v;
                        }
                    }
                }
            }
        }

        if (more)
            dv = make_float4(on.x - ln.x, on.y - ln.y, on.z - ln.z, on.w - ln.w);
        // no second barrier: next iter's barrier orders read(buf) vs write(buf) at i+2
    }

    // wave reduce, then 4 waves -> 1 value per block
    #pragma unroll
    for (int off = 32; off; off >>= 1) acc += __shfl_down(acc, off, 64);
    __shared__ float red[4];
    const int lane = t & 63, wid = t >> 6;
    if (lane == 0) red[wid] = acc;
    __syncthreads();
    if (t == 0) partial[blockIdx.x] = red[0] + red[1] + red[2] + red[3];
}

__global__ __launch_bounds__(THREADS) void cdl_final(
    const float* __restrict__ partial,
    float* __restrict__ out,
    int np,
    float inv_count)
{
    __shared__ float red[THREADS / 64];
    const int t = threadIdx.x;
    float acc = 0.f;
    for (int i = t; i < np; i += THREADS) acc += partial[i];
    #pragma unroll
    for (int off = 32; off; off >>= 1) acc += __shfl_down(acc, off, 64);
    if ((t & 63) == 0) red[t >> 6] = acc;
    __syncthreads();
    if (t == 0) out[0] = (red[0] + red[1] + red[2] + red[3]) * inv_count;
}

extern "C" void kernel_launch(void* const* d_in, const int* in_sizes, int n_in,
                              void* d_out, int out_size, void* d_ws, size_t ws_size,
                              hipStream_t stream) {
    const float* outp = (const float*)d_in[0];
    const float* labp = (const float*)d_in[1];
    float* partial = (float*)d_ws;
    const int nimg = in_sizes[0] / 1024;                  // B (H=W=32)
    const int nblocks = (nimg + IPB - 1) / IPB;           // 2048 for B=16384
    const float inv_count = 1.0f / ((float)nimg * 8.0f * 900.0f);

    cdl_partial<<<nblocks, THREADS, 0, stream>>>(outp, labp, partial, nimg);
    cdl_final<<<1, THREADS, 0, stream>>>(partial, (float*)d_out, nblocks, inv_count);
}